// Round 1
// baseline (1107.860 us; speedup 1.0000x reference)
//
#include <hip/hip_runtime.h>

#define N_NODES 20000
#define N_EDGES 320000
#define HEADS   4
#define DIM     64
#define FEAT    256   // HEADS*DIM

// Per-node gate dot products: gd[n,h] = <h[n,h,:], Wd>, gs[n,h] = <h[n,h,:], Ws>
// One 256-thread block per node; each 64-lane wave handles one head.
__global__ void node_gate_kernel(const float* __restrict__ h,
                                 const float* __restrict__ Wg,
                                 float* __restrict__ gd,
                                 float* __restrict__ gs) {
    int n = blockIdx.x;
    int t = threadIdx.x;          // 0..255
    int head = t >> 6;
    int lane = t & 63;
    float hv = h[(size_t)n * FEAT + t];
    float a = hv * Wg[lane];        // Wd = W_gate[0:64]
    float b = hv * Wg[64 + lane];   // Ws = W_gate[64:128]
#pragma unroll
    for (int off = 32; off; off >>= 1) {
        a += __shfl_xor(a, off);
        b += __shfl_xor(b, off);
    }
    if (lane == 0) {
        gd[n * HEADS + head] = a;
        gs[n * HEADS + head] = b;
    }
}

__global__ void deg_kernel(const int* __restrict__ dst, float* __restrict__ deg) {
    int i = blockIdx.x * blockDim.x + threadIdx.x;
    if (i < N_EDGES) atomicAdd(&deg[dst[i]], 1.0f);
}

__global__ void norm_kernel(const float* __restrict__ deg, float* __restrict__ norm) {
    int i = blockIdx.x * blockDim.x + threadIdx.x;
    if (i < N_NODES) norm[i] = 1.0f / sqrtf(fmaxf(deg[i], 1.0f));
}

// One wave (64 lanes) per edge. Lane l covers feature elements [4l, 4l+4),
// all within head (l>>4). float4 gather of h[src], scaled atomic scatter to z[dst].
__global__ void edge_kernel(const float* __restrict__ h,
                            const int* __restrict__ src,
                            const int* __restrict__ dst,
                            const float* __restrict__ gd,
                            const float* __restrict__ gs,
                            const float* __restrict__ norm,
                            const float* __restrict__ b_gate,
                            float* __restrict__ z) {
    int wave = (blockIdx.x * blockDim.x + threadIdx.x) >> 6;
    int lane = threadIdx.x & 63;
    if (wave >= N_EDGES) return;

    int sn = src[wave];
    int dn = dst[wave];
    int head = lane >> 4;

    float gate = tanhf(gd[dn * HEADS + head] + gs[sn * HEADS + head] + b_gate[0])
               * norm[dn] * norm[sn];

    float4 hv = ((const float4*)(h + (size_t)sn * FEAT))[lane];
    float* zp = z + (size_t)dn * FEAT + lane * 4;
    atomicAdd(zp + 0, hv.x * gate);
    atomicAdd(zp + 1, hv.y * gate);
    atomicAdd(zp + 2, hv.z * gate);
    atomicAdd(zp + 3, hv.w * gate);
}

extern "C" void kernel_launch(void* const* d_in, const int* in_sizes, int n_in,
                              void* d_out, int out_size, void* d_ws, size_t ws_size,
                              hipStream_t stream) {
    const float* h      = (const float*)d_in[0];
    const float* W_gate = (const float*)d_in[1];
    const float* b_gate = (const float*)d_in[2];
    const int*   src    = (const int*)d_in[3];
    const int*   dst    = (const int*)d_in[4];
    float* z = (float*)d_out;

    // Workspace layout (floats): deg[N] | norm[N] | gd[4N] | gs[4N]
    float* deg  = (float*)d_ws;
    float* norm = deg + N_NODES;
    float* gd   = norm + N_NODES;
    float* gs   = gd + N_NODES * HEADS;

    // Zero output accumulator and degree counts (harness does not re-poison).
    hipMemsetAsync(z, 0, (size_t)out_size * sizeof(float), stream);
    hipMemsetAsync(deg, 0, (size_t)N_NODES * sizeof(float), stream);

    node_gate_kernel<<<N_NODES, 256, 0, stream>>>(h, W_gate, gd, gs);
    deg_kernel<<<(N_EDGES + 255) / 256, 256, 0, stream>>>(dst, deg);
    norm_kernel<<<(N_NODES + 255) / 256, 256, 0, stream>>>(deg, norm);

    // 4 waves per 256-thread block -> one edge per wave.
    int edge_blocks = (N_EDGES + 3) / 4;
    edge_kernel<<<edge_blocks, 256, 0, stream>>>(h, src, dst, gd, gs, norm, b_gate, z);
}

// Round 2
// 127.356 us; speedup vs baseline: 8.6989x; 8.6989x over previous
//
#include <hip/hip_runtime.h>

#define N_NODES 20000
#define N_EDGES 320000
#define HEADS   4
#define DIM     64
#define FEAT    256   // HEADS*DIM

// ---------- per-node gate dot products ----------
// gd[n,h] = <h[n,h,:], Wd>, gs[n,h] = <h[n,h,:], Ws>
__global__ void node_gate_kernel(const float* __restrict__ h,
                                 const float* __restrict__ Wg,
                                 float* __restrict__ gd,
                                 float* __restrict__ gs) {
    int n = blockIdx.x;
    int t = threadIdx.x;          // 0..255
    int head = t >> 6;
    int lane = t & 63;
    float hv = h[(size_t)n * FEAT + t];
    float a = hv * Wg[lane];        // Wd = W_gate[0:64]
    float b = hv * Wg[64 + lane];   // Ws = W_gate[64:128]
#pragma unroll
    for (int off = 32; off; off >>= 1) {
        a += __shfl_xor(a, off);
        b += __shfl_xor(b, off);
    }
    if (lane == 0) {
        gd[n * HEADS + head] = a;
        gs[n * HEADS + head] = b;
    }
}

// ---------- degree count (int atomics) ----------
__global__ void deg_kernel(const int* __restrict__ dst, int* __restrict__ deg) {
    int i = blockIdx.x * blockDim.x + threadIdx.x;
    if (i < N_EDGES) atomicAdd(&deg[dst[i]], 1);
}

// ---------- norm from int degree ----------
__global__ void norm_kernel(const int* __restrict__ deg, float* __restrict__ norm) {
    int i = blockIdx.x * blockDim.x + threadIdx.x;
    if (i < N_NODES) norm[i] = rsqrtf(fmaxf((float)deg[i], 1.0f));
}

// ---------- single-block exclusive scan of deg -> offs, cursor ----------
__global__ void scan_kernel(const int* __restrict__ deg,
                            int* __restrict__ offs,
                            int* __restrict__ cursor) {
    __shared__ int wave_sums[16];
    int t = threadIdx.x;          // 0..1023
    int lane = t & 63;
    int wid = t >> 6;             // 0..15
    int carry = 0;
    for (int base = 0; base < N_NODES; base += 1024) {
        int i = base + t;
        int v = (i < N_NODES) ? deg[i] : 0;
        // inclusive wave scan
        int x = v;
#pragma unroll
        for (int off = 1; off < 64; off <<= 1) {
            int y = __shfl_up(x, off);
            if (lane >= off) x += y;
        }
        if (lane == 63) wave_sums[wid] = x;
        __syncthreads();
        if (wid == 0) {
            int s = (lane < 16) ? wave_sums[lane] : 0;
#pragma unroll
            for (int off = 1; off < 16; off <<= 1) {
                int y = __shfl_up(s, off);
                if (lane >= off) s += y;
            }
            if (lane < 16) wave_sums[lane] = s;   // inclusive wave-sum scan
        }
        __syncthreads();
        int wave_base = (wid == 0) ? 0 : wave_sums[wid - 1];
        int incl = x + wave_base + carry;
        if (i < N_NODES) {
            int excl = incl - v;
            offs[i] = excl;
            cursor[i] = excl;
        }
        carry += wave_sums[15];
        __syncthreads();          // protect wave_sums before next round
    }
    if (t == 0) offs[N_NODES] = carry;
}

// ---------- scatter edges into CSR order, precompute per-head gates ----------
__global__ void scatter_kernel(const int* __restrict__ src,
                               const int* __restrict__ dst,
                               const float* __restrict__ gd,
                               const float* __restrict__ gs,
                               const float* __restrict__ norm,
                               const float* __restrict__ b_gate,
                               int* __restrict__ cursor,
                               int* __restrict__ csr_src,
                               float4* __restrict__ csr_gate) {
    int i = blockIdx.x * blockDim.x + threadIdx.x;
    if (i >= N_EDGES) return;
    int sn = src[i];
    int dn = dst[i];
    int pos = atomicAdd(&cursor[dn], 1);
    float nn = norm[dn] * norm[sn];
    float b = b_gate[0];
    float4 g;
    g.x = tanhf(gd[dn * HEADS + 0] + gs[sn * HEADS + 0] + b) * nn;
    g.y = tanhf(gd[dn * HEADS + 1] + gs[sn * HEADS + 1] + b) * nn;
    g.z = tanhf(gd[dn * HEADS + 2] + gs[sn * HEADS + 2] + b) * nn;
    g.w = tanhf(gd[dn * HEADS + 3] + gs[sn * HEADS + 3] + b) * nn;
    csr_src[pos] = sn;
    csr_gate[pos] = g;
}

// ---------- gather-accumulate: one wave per dst node, float4 per lane ----------
__global__ void gather_kernel(const float* __restrict__ h,
                              const int* __restrict__ offs,
                              const int* __restrict__ csr_src,
                              const float* __restrict__ csr_gate,
                              float* __restrict__ z) {
    int wid = (blockIdx.x * blockDim.x + threadIdx.x) >> 6;
    int lane = threadIdx.x & 63;
    if (wid >= N_NODES) return;
    int head = lane >> 4;         // 16 lanes per head, float4 each = 64 floats
    int e0 = offs[wid];
    int e1 = offs[wid + 1];
    const float4* h4 = (const float4*)h;
    float4 acc = make_float4(0.f, 0.f, 0.f, 0.f);
    int e = e0;
    for (; e + 2 <= e1; e += 2) {
        int s0 = csr_src[e];
        int s1 = csr_src[e + 1];
        float g0 = csr_gate[e * 4 + head];
        float g1 = csr_gate[e * 4 + 4 + head];
        float4 v0 = h4[(size_t)s0 * 64 + lane];
        float4 v1 = h4[(size_t)s1 * 64 + lane];
        acc.x += g0 * v0.x; acc.y += g0 * v0.y; acc.z += g0 * v0.z; acc.w += g0 * v0.w;
        acc.x += g1 * v1.x; acc.y += g1 * v1.y; acc.z += g1 * v1.z; acc.w += g1 * v1.w;
    }
    if (e < e1) {
        int s0 = csr_src[e];
        float g0 = csr_gate[e * 4 + head];
        float4 v0 = h4[(size_t)s0 * 64 + lane];
        acc.x += g0 * v0.x; acc.y += g0 * v0.y; acc.z += g0 * v0.z; acc.w += g0 * v0.w;
    }
    ((float4*)z)[(size_t)wid * 64 + lane] = acc;
}

extern "C" void kernel_launch(void* const* d_in, const int* in_sizes, int n_in,
                              void* d_out, int out_size, void* d_ws, size_t ws_size,
                              hipStream_t stream) {
    const float* h      = (const float*)d_in[0];
    const float* W_gate = (const float*)d_in[1];
    const float* b_gate = (const float*)d_in[2];
    const int*   src    = (const int*)d_in[3];
    const int*   dst    = (const int*)d_in[4];
    float* z = (float*)d_out;

    // Workspace layout (16B-aligned chunks):
    char* p = (char*)d_ws;
    int*   deg      = (int*)p;            p += 80000;     // 20000 ints
    int*   offs     = (int*)p;            p += 80016;     // 20001 ints (+pad)
    int*   cursor   = (int*)p;            p += 80000;     // 20000 ints
    float* gd       = (float*)p;          p += 320000;    // 80000 f
    float* gs       = (float*)p;          p += 320000;    // 80000 f
    float* norm     = (float*)p;          p += 80000;     // 20000 f
    int*   csr_src  = (int*)p;            p += 1280000;   // 320000 ints
    float* csr_gate = (float*)p;          p += 5120000;   // 1.28M f (float4-aligned)

    hipMemsetAsync(deg, 0, N_NODES * sizeof(int), stream);

    node_gate_kernel<<<N_NODES, 256, 0, stream>>>(h, W_gate, gd, gs);
    deg_kernel<<<(N_EDGES + 255) / 256, 256, 0, stream>>>(dst, deg);
    norm_kernel<<<(N_NODES + 255) / 256, 256, 0, stream>>>(deg, norm);
    scan_kernel<<<1, 1024, 0, stream>>>(deg, offs, cursor);
    scatter_kernel<<<(N_EDGES + 255) / 256, 256, 0, stream>>>(
        src, dst, gd, gs, norm, b_gate, cursor, csr_src, (float4*)csr_gate);

    // one wave per node: 20000 waves = 5000 blocks of 256 threads
    gather_kernel<<<(N_NODES * 64 + 255) / 256, 256, 0, stream>>>(
        h, offs, csr_src, csr_gate, z);
}

// Round 3
// 124.803 us; speedup vs baseline: 8.8769x; 1.0205x over previous
//
#include <hip/hip_runtime.h>
#include <hip/hip_bf16.h>

#define N_NODES 20000
#define N_EDGES 320000
#define HEADS   4
#define FEAT    256   // HEADS*64

// ---------- fused prep: gate dots + bf16 convert + degree count ----------
// One 256-thread block per node. Also: global threads < N_EDGES count degrees.
__global__ void prep_kernel(const float* __restrict__ h,
                            const float* __restrict__ Wg,
                            const int* __restrict__ dst,
                            float* __restrict__ gd,
                            float* __restrict__ gs,
                            unsigned short* __restrict__ hb,
                            int* __restrict__ deg) {
    int n = blockIdx.x;
    int t = threadIdx.x;          // 0..255
    int head = t >> 6;
    int lane = t & 63;
    size_t idx = (size_t)n * FEAT + t;
    float hv = h[idx];

    // bf16 copy of h (round-to-nearest)
    __hip_bfloat16 hbv = __float2bfloat16(hv);
    hb[idx] = *reinterpret_cast<unsigned short*>(&hbv);

    // degree count piggy-back (first 1250 blocks)
    int gid = n * 256 + t;
    if (gid < N_EDGES) atomicAdd(&deg[dst[gid]], 1);

    float a = hv * Wg[lane];        // Wd = W_gate[0:64]
    float b = hv * Wg[64 + lane];   // Ws = W_gate[64:128]
#pragma unroll
    for (int off = 32; off; off >>= 1) {
        a += __shfl_xor(a, off);
        b += __shfl_xor(b, off);
    }
    if (lane == 0) {
        gd[n * HEADS + head] = a;
        gs[n * HEADS + head] = b;
    }
}

// ---------- single-round scan of deg -> offs/cursor, fused norm ----------
#define CHUNK 20   // 1024 * 20 = 20480 >= N_NODES
__global__ void scan_kernel(const int* __restrict__ deg,
                            int* __restrict__ offs,
                            int* __restrict__ cursor,
                            float* __restrict__ norm) {
    __shared__ int wsum[16];
    int t = threadIdx.x;          // 0..1023
    int lane = t & 63;
    int wid = t >> 6;
    int base = t * CHUNK;

    int v[CHUNK];
    int s = 0;
#pragma unroll
    for (int j = 0; j < CHUNK; ++j) {
        int i = base + j;
        v[j] = (i < N_NODES) ? deg[i] : 0;
        s += v[j];
    }
    // inclusive scan of per-thread sums across 1024 threads
    int x = s;
#pragma unroll
    for (int off = 1; off < 64; off <<= 1) {
        int y = __shfl_up(x, off);
        if (lane >= off) x += y;
    }
    if (lane == 63) wsum[wid] = x;
    __syncthreads();
    if (wid == 0) {
        int ws = (lane < 16) ? wsum[lane] : 0;
#pragma unroll
        for (int off = 1; off < 16; off <<= 1) {
            int y = __shfl_up(ws, off);
            if (lane >= off) ws += y;
        }
        if (lane < 16) wsum[lane] = ws;
    }
    __syncthreads();
    int wbase = (wid == 0) ? 0 : wsum[wid - 1];
    int excl = wbase + (x - s);   // global exclusive prefix of this thread's chunk
#pragma unroll
    for (int j = 0; j < CHUNK; ++j) {
        int i = base + j;
        if (i < N_NODES) {
            offs[i] = excl;
            cursor[i] = excl;
            norm[i] = rsqrtf(fmaxf((float)v[j], 1.0f));
            excl += v[j];
        }
    }
    if (t == 1023) offs[N_NODES] = excl;   // == N_EDGES
}

// ---------- scatter: CSR src index only (4B/edge) ----------
__global__ void scatter_kernel(const int* __restrict__ src,
                               const int* __restrict__ dst,
                               int* __restrict__ cursor,
                               int* __restrict__ csr_src) {
    int i = blockIdx.x * blockDim.x + threadIdx.x;
    if (i >= N_EDGES) return;
    int sn = src[i];
    int dn = dst[i];
    int pos = atomicAdd(&cursor[dn], 1);
    csr_src[pos] = sn;
}

// ---------- gather-accumulate: one wave per dst node, inline gates ----------
__global__ void gather_kernel(const unsigned short* __restrict__ hb,
                              const int* __restrict__ offs,
                              const int* __restrict__ csr_src,
                              const float* __restrict__ gd,
                              const float* __restrict__ gs,
                              const float* __restrict__ norm,
                              const float* __restrict__ bg,
                              float* __restrict__ z) {
    int wid = (blockIdx.x * blockDim.x + threadIdx.x) >> 6;
    int lane = threadIdx.x & 63;
    if (wid >= N_NODES) return;
    int head = lane >> 4;
    int e0 = offs[wid];
    int e1 = offs[wid + 1];
    float gb = gd[wid * HEADS + head] + bg[0];  // gate base (dst part + bias)
    float nd = norm[wid];
    const ushort4* h4 = (const ushort4*)hb;     // row stride = 64 ushort4
    float4 acc = make_float4(0.f, 0.f, 0.f, 0.f);

    for (int base = e0; base < e1; base += 64) {
        int sreg = 0;
        if (base + lane < e1) sreg = csr_src[base + lane];
        int cnt = min(64, e1 - base);
#pragma unroll 4
        for (int j = 0; j < cnt; ++j) {
            int sn = __shfl(sreg, j);
            float gsv = gs[sn * HEADS + head];
            float ns = norm[sn];
            ushort4 r = h4[(size_t)sn * 64 + lane];
            float gate = tanhf(gb + gsv) * nd * ns;
            float4 hv;
            hv.x = __uint_as_float((unsigned)r.x << 16);
            hv.y = __uint_as_float((unsigned)r.y << 16);
            hv.z = __uint_as_float((unsigned)r.z << 16);
            hv.w = __uint_as_float((unsigned)r.w << 16);
            acc.x += gate * hv.x;
            acc.y += gate * hv.y;
            acc.z += gate * hv.z;
            acc.w += gate * hv.w;
        }
    }
    ((float4*)z)[(size_t)wid * 64 + lane] = acc;
}

extern "C" void kernel_launch(void* const* d_in, const int* in_sizes, int n_in,
                              void* d_out, int out_size, void* d_ws, size_t ws_size,
                              hipStream_t stream) {
    const float* h      = (const float*)d_in[0];
    const float* W_gate = (const float*)d_in[1];
    const float* b_gate = (const float*)d_in[2];
    const int*   src    = (const int*)d_in[3];
    const int*   dst    = (const int*)d_in[4];
    float* z = (float*)d_out;

    // Workspace layout (all 16B aligned):
    char* p = (char*)d_ws;
    int*   deg     = (int*)p;             p += 80000;      // 20000 i32
    int*   offs    = (int*)p;             p += 80016;      // 20001 i32 (+pad)
    int*   cursor  = (int*)p;             p += 80000;      // 20000 i32
    float* gd      = (float*)p;           p += 320000;     // 80000 f32
    float* gs      = (float*)p;           p += 320000;     // 80000 f32
    float* norm    = (float*)p;           p += 80000;      // 20000 f32
    int*   csr_src = (int*)p;             p += 1280000;    // 320000 i32
    unsigned short* hb = (unsigned short*)p; p += 10240000; // 5.12M bf16 (~12.4 MB total)

    hipMemsetAsync(deg, 0, N_NODES * sizeof(int), stream);

    prep_kernel<<<N_NODES, 256, 0, stream>>>(h, W_gate, dst, gd, gs, hb, deg);
    scan_kernel<<<1, 1024, 0, stream>>>(deg, offs, cursor, norm);
    scatter_kernel<<<(N_EDGES + 255) / 256, 256, 0, stream>>>(src, dst, cursor, csr_src);
    gather_kernel<<<(N_NODES * 64 + 255) / 256, 256, 0, stream>>>(
        hb, offs, csr_src, gd, gs, norm, b_gate, z);
}